// Round 2
// baseline (1775.392 us; speedup 1.0000x reference)
//
#include <hip/hip_runtime.h>
#include <math.h>

#define HWSZ 4096

// Wave-local LDS fence: drain this wave's DS queue. All cross-lane traffic in
// spe_main is wave-internal (per-wave LDS regions), so no block barrier needed.
#define WFENCE() asm volatile("s_waitcnt lgkmcnt(0)" ::: "memory")

__device__ __forceinline__ float sigmoid_f(float x){ return 1.0f/(1.0f + __expf(-x)); }
__device__ __forceinline__ float silu_f(float x){ return x * sigmoid_f(x); }
__device__ __forceinline__ float softplus_f(float x){ return fmaxf(x,0.0f) + __logf(1.0f + __expf(-fabsf(x))); }

// Kernel 1: per-wave sequence processing, waves fully decoupled after weight staging.
// grid 2048 blocks x 256 threads. Block handles 16 consecutive sequences
// (same b, 16 consecutive hw); wave w handles seqs base + k*4 + w, k=0..3.
// lane = d_inner channel (64 lanes = D_INNER).
__global__ __launch_bounds__(256, 3) void spe_main(
    const float* __restrict__ x,
    const float* __restrict__ in_proj_w,
    const float* __restrict__ conv_w_f, const float* __restrict__ conv_b_f,
    const float* __restrict__ conv_w_b, const float* __restrict__ conv_b_b,
    const float* __restrict__ x_proj_w_f, const float* __restrict__ x_proj_w_b,
    const float* __restrict__ dt_proj_w_f, const float* __restrict__ dt_proj_b_f,
    const float* __restrict__ dt_proj_w_b, const float* __restrict__ dt_proj_b_b,
    const float* __restrict__ A_log_f, const float* __restrict__ A_log_b,
    const float* __restrict__ D_f, const float* __restrict__ D_b,
    const float* __restrict__ out_proj_w,
    float* __restrict__ out, float* __restrict__ sums)
{
    // x_proj weights pair-interleaved: xw2[d2*68 + bj] = {W[j][2*d2], W[j][2*d2+1]}
    // bj = branch*34 + j. Lane-consecutive bj -> 8B stride -> 2-way b64 (free).
    __shared__ __align__(16) float2 xw2[32*68];
    __shared__ __align__(16) float fy_lds[4][512];      // union: xf [t*32+m] (256) / y [t*64+d] (512)
    __shared__ __align__(16) float uc_lds[4][2][8][64]; // [wave][branch][t][d]
    __shared__ __align__(16) float dbl_lds[4][576];     // [wave][(t*2+br)*36 + slot]; dt:0-1 B:4-19 C:20-35

    const int tid = threadIdx.x;
    const int wid = tid >> 6;
    const int l   = tid & 63;

    // stage x_proj weights (one-time, block-shared)
    for (int idx = tid; idx < 32*68; idx += 256){
        int d2 = idx / 68, bj = idx - d2*68;
        const float* w = (bj < 34) ? x_proj_w_f : x_proj_w_b;
        int j = (bj < 34) ? bj : bj - 34;
        xw2[idx] = make_float2(w[j*64 + 2*d2], w[j*64 + 2*d2 + 1]);
    }

    // ---- per-lane weights in registers ----
    float w_u[32], w_z[32], w_o[64], A_f[16], A_b[16];
    {
        const float4* pu = (const float4*)(in_proj_w + l*32);
        const float4* pz = (const float4*)(in_proj_w + (64+l)*32);
        #pragma unroll
        for (int m4=0;m4<8;m4++){
            float4 a = pu[m4];
            w_u[m4*4+0]=a.x; w_u[m4*4+1]=a.y; w_u[m4*4+2]=a.z; w_u[m4*4+3]=a.w;
            float4 c = pz[m4];
            w_z[m4*4+0]=c.x; w_z[m4*4+1]=c.y; w_z[m4*4+2]=c.z; w_z[m4*4+3]=c.w;
        }
        const float4* po = (const float4*)(out_proj_w + (l&31)*64);
        #pragma unroll
        for (int m4=0;m4<16;m4++){
            float4 a = po[m4];
            w_o[m4*4+0]=a.x; w_o[m4*4+1]=a.y; w_o[m4*4+2]=a.z; w_o[m4*4+3]=a.w;
        }
        const float4* pa = (const float4*)(A_log_f + l*16);
        const float4* pb = (const float4*)(A_log_b + l*16);
        #pragma unroll
        for (int s4=0;s4<4;s4++){
            float4 a = pa[s4];
            A_f[s4*4+0]=-__expf(a.x); A_f[s4*4+1]=-__expf(a.y);
            A_f[s4*4+2]=-__expf(a.z); A_f[s4*4+3]=-__expf(a.w);
            float4 c = pb[s4];
            A_b[s4*4+0]=-__expf(c.x); A_b[s4*4+1]=-__expf(c.y);
            A_b[s4*4+2]=-__expf(c.z); A_b[s4*4+3]=-__expf(c.w);
        }
    }
    const float cw0f=conv_w_f[l*2], cw1f=conv_w_f[l*2+1], cbf=conv_b_f[l];
    const float cw0b=conv_w_b[l*2], cw1b=conv_w_b[l*2+1], cbb=conv_b_b[l];
    const float dtw0f=dt_proj_w_f[l*2], dtw1f=dt_proj_w_f[l*2+1], dtbf=dt_proj_b_f[l];
    const float dtw0b=dt_proj_w_b[l*2], dtw1b=dt_proj_w_b[l*2+1], dtbb=dt_proj_b_b[l];
    const float Dfv=D_f[l], Dbv=D_b[l];

    const int b = blockIdx.x >> 8;             // 256 blocks per batch
    const int hwbase = (blockIdx.x & 255) * 16;
    const float* xb = x + b*(256*HWSZ);
    float* outb0 = out + b*(256*HWSZ);

    float gs[4] = {0,0,0,0};  // group sums (group == r, since c = r*64 + lane)
    float gq[4] = {0,0,0,0};

    __syncthreads();          // xw2 visible to all waves; the ONLY block barrier

    #pragma unroll 1
    for (int k=0;k<4;k++){
        const int hw = hwbase + k*4 + wid;

        WFENCE();  // prior k's y-reads (fy union) complete before xf rewrite

        // stage this sequence's tokens: xf[t*32+m] = x[b, c=t*32+m, hw]
        #pragma unroll
        for (int r=0;r<4;r++)
            fy_lds[wid][r*64 + l] = xb[(r*64 + l)*HWSZ + hw];
        WFENCE();

        // ---- in_proj: u[t] = xf[t]·w_u(lane), z -> silu(z) ----
        float u[8], siluz[8];
        #pragma unroll
        for (int t=0;t<8;t++){
            const float4* xf4 = (const float4*)&fy_lds[wid][t*32];
            float au0=0,au1=0,au2=0,au3=0, az0=0,az1=0,az2=0,az3=0;
            #pragma unroll
            for (int m4=0;m4<8;m4++){
                float4 xv = xf4[m4];
                au0 = fmaf(xv.x, w_u[m4*4+0], au0);
                au1 = fmaf(xv.y, w_u[m4*4+1], au1);
                au2 = fmaf(xv.z, w_u[m4*4+2], au2);
                au3 = fmaf(xv.w, w_u[m4*4+3], au3);
                az0 = fmaf(xv.x, w_z[m4*4+0], az0);
                az1 = fmaf(xv.y, w_z[m4*4+1], az1);
                az2 = fmaf(xv.z, w_z[m4*4+2], az2);
                az3 = fmaf(xv.w, w_z[m4*4+3], az3);
            }
            u[t] = (au0+au1)+(au2+au3);
            siluz[t] = silu_f((az0+az1)+(az2+az3));
        }

        // ---- causal conv (fwd & flipped) + silu ----
        float ucf[8], ucb[8];
        #pragma unroll
        for (int t=0;t<8;t++){
            float prev = (t>0)? u[t-1] : 0.0f;
            ucf[t] = silu_f(fmaf(prev, cw0f, fmaf(u[t], cw1f, cbf)));
        }
        #pragma unroll
        for (int t=0;t<8;t++){            // backward branch operates on flip(u)
            float prev = (t>0)? u[8-t] : 0.0f;
            ucb[t] = silu_f(fmaf(prev, cw0b, fmaf(u[7-t], cw1b, cbb)));
        }
        #pragma unroll
        for (int t=0;t<8;t++){ uc_lds[wid][0][t][l]=ucf[t]; uc_lds[wid][1][t][l]=ucb[t]; }
        WFENCE();  // uc visible; also ensures prev-k dbl reads drained before rewrite

        // ---- x_proj: 8 tokens x 2 branches x 34 outputs = 544 dot products over d=64 ----
        for (int k2=0;k2<9;k2++){
            int o = k2*64 + l;
            int act = (o < 544) ? 1 : 0;
            int oc = act ? o : 0;
            int t = oc / 68;
            int r68 = oc - t*68;
            int br = (r68 >= 34) ? 1 : 0;
            int j = r68 - br*34;
            const float4* ucp = (const float4*)&uc_lds[wid][br][t][0];
            const float2* wp2 = &xw2[br*34 + j];
            float a0=0,a1=0,a2=0,a3=0;
            #pragma unroll
            for (int d4=0; d4<16; d4++){
                float4 uv = ucp[d4];
                float2 wA = wp2[(d4*2+0)*68];
                float2 wB = wp2[(d4*2+1)*68];
                a0 = fmaf(uv.x, wA.x, a0);
                a1 = fmaf(uv.y, wA.y, a1);
                a2 = fmaf(uv.z, wB.x, a2);
                a3 = fmaf(uv.w, wB.y, a3);
            }
            if (act){
                int jm = j + ((j>=2)?2:0);     // dt->0..1, B->4..19, C->20..35
                dbl_lds[wid][(t*2+br)*36 + jm] = (a0+a1)+(a2+a3);
            }
        }
        WFENCE();

        // ---- selective scans (lane d keeps h[16]) ----
        float h[16], yf[8];
        #pragma unroll
        for (int s=0;s<16;s++) h[s]=0.0f;
        #pragma unroll
        for (int t=0;t<8;t++){
            const float* sl = &dbl_lds[wid][(t*2+0)*36];
            float delta = softplus_f(fmaf(sl[0], dtw0f, fmaf(sl[1], dtw1f, dtbf)));
            float du = delta * ucf[t];
            const float4* B4 = (const float4*)(sl+4);
            const float4* C4 = (const float4*)(sl+20);
            float y=0.0f;
            #pragma unroll
            for (int s4=0;s4<4;s4++){
                float4 Bv=B4[s4], Cv=C4[s4];
                float e0=__expf(delta*A_f[s4*4+0]);
                h[s4*4+0]=fmaf(e0,h[s4*4+0],du*Bv.x); y=fmaf(h[s4*4+0],Cv.x,y);
                float e1=__expf(delta*A_f[s4*4+1]);
                h[s4*4+1]=fmaf(e1,h[s4*4+1],du*Bv.y); y=fmaf(h[s4*4+1],Cv.y,y);
                float e2=__expf(delta*A_f[s4*4+2]);
                h[s4*4+2]=fmaf(e2,h[s4*4+2],du*Bv.z); y=fmaf(h[s4*4+2],Cv.z,y);
                float e3=__expf(delta*A_f[s4*4+3]);
                h[s4*4+3]=fmaf(e3,h[s4*4+3],du*Bv.w); y=fmaf(h[s4*4+3],Cv.w,y);
            }
            yf[t] = fmaf(Dfv, ucf[t], y);
        }
        #pragma unroll
        for (int s=0;s<16;s++) h[s]=0.0f;
        #pragma unroll
        for (int tau=0;tau<8;tau++){
            const float* sl = &dbl_lds[wid][(tau*2+1)*36];
            float delta = softplus_f(fmaf(sl[0], dtw0b, fmaf(sl[1], dtw1b, dtbb)));
            float du = delta * ucb[tau];
            const float4* B4 = (const float4*)(sl+4);
            const float4* C4 = (const float4*)(sl+20);
            float y=0.0f;
            #pragma unroll
            for (int s4=0;s4<4;s4++){
                float4 Bv=B4[s4], Cv=C4[s4];
                float e0=__expf(delta*A_b[s4*4+0]);
                h[s4*4+0]=fmaf(e0,h[s4*4+0],du*Bv.x); y=fmaf(h[s4*4+0],Cv.x,y);
                float e1=__expf(delta*A_b[s4*4+1]);
                h[s4*4+1]=fmaf(e1,h[s4*4+1],du*Bv.y); y=fmaf(h[s4*4+1],Cv.y,y);
                float e2=__expf(delta*A_b[s4*4+2]);
                h[s4*4+2]=fmaf(e2,h[s4*4+2],du*Bv.z); y=fmaf(h[s4*4+2],Cv.z,y);
                float e3=__expf(delta*A_b[s4*4+3]);
                h[s4*4+3]=fmaf(e3,h[s4*4+3],du*Bv.w); y=fmaf(h[s4*4+3],Cv.w,y);
            }
            float ytb = fmaf(Dbv, ucb[tau], y);
            int t = 7-tau;                 // un-flip
            fy_lds[wid][t*64 + l] = (yf[t] + ytb) * siluz[t];
        }
        WFENCE();

        // ---- out_proj (lane l -> channel c = r*64 + l, row m = l&31) + GN partials ----
        {
            const int half = l >> 5;
            float* outp = outb0 + hw;
            #pragma unroll
            for (int r=0;r<4;r++){
                int t = 2*r + half;
                const float4* yp = (const float4*)&fy_lds[wid][t*64];
                float a0=0,a1=0,a2=0,a3=0;
                #pragma unroll
                for (int d4=0; d4<16; d4++){
                    float4 yv = yp[d4];
                    a0=fmaf(yv.x, w_o[d4*4+0], a0);
                    a1=fmaf(yv.y, w_o[d4*4+1], a1);
                    a2=fmaf(yv.z, w_o[d4*4+2], a2);
                    a3=fmaf(yv.w, w_o[d4*4+3], a3);
                }
                float val = (a0+a1)+(a2+a3);
                outp[(r*64 + l)*HWSZ] = val;   // pre-GN, (B,C,H,W) layout
                gs[r] += val;
                gq[r] = fmaf(val, val, gq[r]);
            }
        }
    }

    // ---- wave-reduce GN partials, one atomic pair per (wave, group) ----
    #pragma unroll
    for (int r=0;r<4;r++){
        float s = gs[r], q = gq[r];
        #pragma unroll
        for (int off=32; off>=1; off>>=1){
            s += __shfl_xor(s, off, 64);
            q += __shfl_xor(q, off, 64);
        }
        if (l==0){
            atomicAdd(&sums[b*8 + r*2],     s);
            atomicAdd(&sums[b*8 + r*2 + 1], q);
        }
    }
}

// Kernel 2: in-place GroupNorm apply + SiLU + residual. 4 floats/thread.
__global__ void spe_gn(float* __restrict__ out, const float* __restrict__ x,
                       const float* __restrict__ sums,
                       const float* __restrict__ gn_w, const float* __restrict__ gn_b)
{
    int i = (blockIdx.x*256 + threadIdx.x)*4;
    int c = (i >> 12) & 255;
    int b = i >> 20;
    int g = c >> 6;
    float s = sums[b*8 + g*2];
    float q = sums[b*8 + g*2 + 1];
    const float invN = 1.0f/262144.0f;   // 64 channels * 4096 hw
    float mean = s*invN;
    float var  = fmaf(-mean, mean, q*invN);
    float rstd = rsqrtf(var + 1e-5f);
    float wv = gn_w[c]*rstd;
    float bv = fmaf(-mean, wv, gn_b[c]);
    float4 o  = *(const float4*)(out + i);
    float4 xv = *(const float4*)(x + i);
    float v0 = fmaf(o.x, wv, bv);
    float v1 = fmaf(o.y, wv, bv);
    float v2 = fmaf(o.z, wv, bv);
    float v3 = fmaf(o.w, wv, bv);
    float4 res;
    res.x = xv.x + v0*sigmoid_f(v0);
    res.y = xv.y + v1*sigmoid_f(v1);
    res.z = xv.z + v2*sigmoid_f(v2);
    res.w = xv.w + v3*sigmoid_f(v3);
    *(float4*)(out + i) = res;
}

extern "C" void kernel_launch(void* const* d_in, const int* in_sizes, int n_in,
                              void* d_out, int out_size, void* d_ws, size_t ws_size,
                              hipStream_t stream) {
    (void)in_sizes; (void)n_in; (void)out_size; (void)ws_size;
    const float* x          = (const float*)d_in[0];
    const float* in_proj_w  = (const float*)d_in[1];
    const float* conv_w_f   = (const float*)d_in[2];
    const float* conv_b_f   = (const float*)d_in[3];
    const float* conv_w_b   = (const float*)d_in[4];
    const float* conv_b_b   = (const float*)d_in[5];
    const float* x_proj_w_f = (const float*)d_in[6];
    const float* x_proj_w_b = (const float*)d_in[7];
    const float* dt_proj_w_f= (const float*)d_in[8];
    const float* dt_proj_b_f= (const float*)d_in[9];
    const float* dt_proj_w_b= (const float*)d_in[10];
    const float* dt_proj_b_b= (const float*)d_in[11];
    const float* A_log_f    = (const float*)d_in[12];
    const float* A_log_b    = (const float*)d_in[13];
    const float* D_f        = (const float*)d_in[14];
    const float* D_b        = (const float*)d_in[15];
    const float* out_proj_w = (const float*)d_in[16];
    const float* gn_w       = (const float*)d_in[17];
    const float* gn_b       = (const float*)d_in[18];
    float* out  = (float*)d_out;
    float* sums = (float*)d_ws;

    hipMemsetAsync(d_ws, 0, 64*sizeof(float), stream);
    spe_main<<<2048, 256, 0, stream>>>(x, in_proj_w,
        conv_w_f, conv_b_f, conv_w_b, conv_b_b,
        x_proj_w_f, x_proj_w_b,
        dt_proj_w_f, dt_proj_b_f, dt_proj_w_b, dt_proj_b_b,
        A_log_f, A_log_b, D_f, D_b, out_proj_w, out, sums);
    spe_gn<<<8192, 256, 0, stream>>>(out, x, sums, gn_w, gn_b);
}

// Round 3
// 518.686 us; speedup vs baseline: 3.4229x; 3.4229x over previous
//
#include <hip/hip_runtime.h>
#include <math.h>

#define HWSZ 4096

// Wave-local LDS fence: drain this wave's DS queue. All cross-lane traffic in
// spe_main is wave-internal (per-wave LDS regions), so no block barrier needed.
#define WFENCE() asm volatile("s_waitcnt lgkmcnt(0)" ::: "memory")

typedef __attribute__((ext_vector_type(8))) short s16x8;
typedef __attribute__((ext_vector_type(4))) float f32x4;

__device__ __forceinline__ float sigmoid_f(float x){ return 1.0f/(1.0f + __expf(-x)); }
__device__ __forceinline__ float silu_f(float x){ return x * sigmoid_f(x); }
__device__ __forceinline__ float softplus_f(float x){ return fmaxf(x,0.0f) + __logf(1.0f + __expf(-fabsf(x))); }

__device__ __forceinline__ short bf16_rn(float f){
    union { float f; unsigned u; } v; v.f = f;
    unsigned r = v.u + 0x7FFFu + ((v.u >> 16) & 1u);
    return (short)(r >> 16);
}
__device__ __forceinline__ float bf16f(short h){
    union { unsigned u; float f; } v; v.u = ((unsigned)(unsigned short)h) << 16; return v.f;
}
// hi-only pack of 8 floats (two float4s)
__device__ __forceinline__ s16x8 pack_hi8(float4 a, float4 b){
    s16x8 r;
    r[0]=bf16_rn(a.x); r[1]=bf16_rn(a.y); r[2]=bf16_rn(a.z); r[3]=bf16_rn(a.w);
    r[4]=bf16_rn(b.x); r[5]=bf16_rn(b.y); r[6]=bf16_rn(b.z); r[7]=bf16_rn(b.w);
    return r;
}
// hi+lo split pack of 8 floats
__device__ __forceinline__ void pack_hilo8(const float* p, s16x8& hi, s16x8& lo){
    #pragma unroll
    for (int i=0;i<8;i++){
        short h = bf16_rn(p[i]); hi[i]=h;
        lo[i] = bf16_rn(p[i] - bf16f(h));
    }
}
__device__ __forceinline__ f32x4 mfma16(s16x8 a, s16x8 b, f32x4 c){
    return __builtin_amdgcn_mfma_f32_16x16x32_bf16(a, b, c, 0, 0, 0);
}

// grid 2048 blocks x 256 threads. Block = 16 consecutive hw (one batch b).
// Wave wid owns hw = hwbase + wid*4 + {0..3}; k-loop of 2 iters x 2 seqs.
// MFMA M=16 rows: in/out_proj rows=(s,t); x_proj rows=(br,t) per seq.
__global__ __launch_bounds__(256, 2) void spe_main(
    const float* __restrict__ x,
    const float* __restrict__ in_proj_w,
    const float* __restrict__ conv_w_f, const float* __restrict__ conv_b_f,
    const float* __restrict__ conv_w_b, const float* __restrict__ conv_b_b,
    const float* __restrict__ x_proj_w_f, const float* __restrict__ x_proj_w_b,
    const float* __restrict__ dt_proj_w_f, const float* __restrict__ dt_proj_b_f,
    const float* __restrict__ dt_proj_w_b, const float* __restrict__ dt_proj_b_b,
    const float* __restrict__ A_log_f, const float* __restrict__ A_log_b,
    const float* __restrict__ D_f, const float* __restrict__ D_b,
    const float* __restrict__ out_proj_w,
    float* __restrict__ out, float* __restrict__ sums)
{
    // Per-wave LDS regions (no inter-wave traffic). Strides padded: row stride
    // 36/68 keeps b128 16B-aligned and banks at free 2-way; 132 for uz writes.
    __shared__ __align__(16) float fy_s[4][1088];   // xf2 [row=(s,t)][m] stride 36  UNION  y2 [row=(s,t)][d] stride 68
    __shared__ __align__(16) float uz_s[4][2112];   // [row=(s,t)][n0..127] stride 132 (u: n<64, z: n>=64)
    __shared__ __align__(16) float uc_s[4][1088];   // [row=(br,t)][d] stride 68
    __shared__ __align__(16) float dbl_s[4][576];   // [(t*2+br)*36 + slot]; dt:0-1 B:4-19 C:20-35

    const int tid = threadIdx.x;
    const int wid = tid >> 6;
    const int l   = tid & 63;
    const int q   = l >> 4;       // quad
    const int c16 = l & 15;

    float* fyW  = &fy_s[wid][0];
    float* uzW  = &uz_s[wid][0];
    float* ucW  = &uc_s[wid][0];
    float* dblW = &dbl_s[wid][0];

    // ---- B-fragments in registers (bf16 hi). B[k][n]: lane holds n=c16(+tile), k=q*8+jj ----
    s16x8 Bin[8];                 // in_proj: K=32 (m), N=128 tiles
    #pragma unroll
    for (int nt=0; nt<8; nt++){
        const float* p = in_proj_w + (nt*16 + c16)*32 + q*8;
        Bin[nt] = pack_hi8(*(const float4*)p, *(const float4*)(p+4));
    }
    s16x8 BxF[3][2], BxB[3][2];   // x_proj: K=64 (d, 2 halves), N=34->3 tiles
    #pragma unroll
    for (int nt=0; nt<3; nt++){
        int j = nt*16 + c16; if (j > 33) j = 0;   // cols >=34 never stored
        #pragma unroll
        for (int kk=0; kk<2; kk++){
            const float* pf = x_proj_w_f + j*64 + kk*32 + q*8;
            const float* pb = x_proj_w_b + j*64 + kk*32 + q*8;
            BxF[nt][kk] = pack_hi8(*(const float4*)pf, *(const float4*)(pf+4));
            BxB[nt][kk] = pack_hi8(*(const float4*)pb, *(const float4*)(pb+4));
        }
    }
    s16x8 Bo[2][2];               // out_proj: K=64 (d), N=32 -> 2 tiles
    #pragma unroll
    for (int nt=0; nt<2; nt++)
        #pragma unroll
        for (int kk=0; kk<2; kk++){
            const float* p = out_proj_w + (nt*16 + c16)*64 + kk*32 + q*8;
            Bo[nt][kk] = pack_hi8(*(const float4*)p, *(const float4*)(p+4));
        }

    // ---- per-lane scan params (lane = d channel) ----
    float A_f[16], A_b[16];
    {
        const float4* pa = (const float4*)(A_log_f + l*16);
        const float4* pb = (const float4*)(A_log_b + l*16);
        #pragma unroll
        for (int s4=0;s4<4;s4++){
            float4 a = pa[s4];
            A_f[s4*4+0]=-__expf(a.x); A_f[s4*4+1]=-__expf(a.y);
            A_f[s4*4+2]=-__expf(a.z); A_f[s4*4+3]=-__expf(a.w);
            float4 c = pb[s4];
            A_b[s4*4+0]=-__expf(c.x); A_b[s4*4+1]=-__expf(c.y);
            A_b[s4*4+2]=-__expf(c.z); A_b[s4*4+3]=-__expf(c.w);
        }
    }
    const float cw0f=conv_w_f[l*2], cw1f=conv_w_f[l*2+1], cbf=conv_b_f[l];
    const float cw0b=conv_w_b[l*2], cw1b=conv_w_b[l*2+1], cbb=conv_b_b[l];
    const float dtw0f=dt_proj_w_f[l*2], dtw1f=dt_proj_w_f[l*2+1], dtbf=dt_proj_b_f[l];
    const float dtw0b=dt_proj_w_b[l*2], dtw1b=dt_proj_w_b[l*2+1], dtbb=dt_proj_b_b[l];
    const float Dfv=D_f[l], Dbv=D_b[l];

    const int b = blockIdx.x >> 8;             // 256 blocks per batch
    const int hwbase = (blockIdx.x & 255) * 16;
    const float* xb = x + b*(256*HWSZ);
    float* outb0 = out + b*(256*HWSZ);

    const f32x4 z4 = {0.f,0.f,0.f,0.f};
    float g_s[2] = {0,0}, g_q[2] = {0,0};      // groups (q&1)*2 + {0,1}

    #pragma unroll 1
    for (int k=0;k<2;k++){
        const int hw0 = hwbase + wid*4 + k*2;  // seqs hw0, hw0+1

        WFENCE();  // prev iter's y2/uz reads drained before overwrite

        // ---- stage xf2: lane loads x[c][hw0..hw0+1], c = r*64+l ----
        float2 xv[4];
        #pragma unroll
        for (int r=0;r<4;r++)
            xv[r] = *(const float2*)(xb + (r*64 + l)*HWSZ + hw0);
        #pragma unroll
        for (int r=0;r<4;r++){
            int t = r*2 + (l>>5), m = l & 31;
            fyW[(0*8 + t)*36 + m] = xv[r].x;
            fyW[(1*8 + t)*36 + m] = xv[r].y;
        }
        WFENCE();

        // ---- in_proj MFMA: A[row=(s,t)][k=m], K=32 ----
        {
            const float* ap = &fyW[(l&15)*36 + q*8];
            float av[8];
            float4 a0 = *(const float4*)ap, a1 = *(const float4*)(ap+4);
            av[0]=a0.x;av[1]=a0.y;av[2]=a0.z;av[3]=a0.w;
            av[4]=a1.x;av[5]=a1.y;av[6]=a1.z;av[7]=a1.w;
            s16x8 Ah, Al; pack_hilo8(av, Ah, Al);
            f32x4 accI[8];
            #pragma unroll
            for (int nt=0; nt<8; nt++){
                f32x4 acc = mfma16(Al, Bin[nt], z4);
                accI[nt]  = mfma16(Ah, Bin[nt], acc);
            }
            WFENCE();  // xf2 frag reads done (union with y2 written later)
            #pragma unroll
            for (int nt=0; nt<8; nt++)
                #pragma unroll
                for (int r=0;r<4;r++)
                    uzW[(q*4 + r)*132 + nt*16 + c16] = accI[nt][r];
        }
        WFENCE();

        // ---- per-sequence: conv + x_proj MFMA + scans ----
        #pragma unroll 1
        for (int s=0;s<2;s++){
            float u[8], siluz[8];
            #pragma unroll
            for (int t=0;t<8;t++){
                u[t]     = uzW[(s*8 + t)*132 + l];
                siluz[t] = uzW[(s*8 + t)*132 + 64 + l];
            }
            #pragma unroll
            for (int t=0;t<8;t++) siluz[t] = silu_f(siluz[t]);

            float ucf[8], ucb[8];
            #pragma unroll
            for (int t=0;t<8;t++){
                float prev = (t>0)? u[t-1] : 0.0f;
                ucf[t] = silu_f(fmaf(prev, cw0f, fmaf(u[t], cw1f, cbf)));
            }
            #pragma unroll
            for (int t=0;t<8;t++){          // backward branch on flip(u)
                float prev = (t>0)? u[8-t] : 0.0f;
                ucb[t] = silu_f(fmaf(prev, cw0b, fmaf(u[7-t], cw1b, cbb)));
            }
            #pragma unroll
            for (int t=0;t<8;t++){
                ucW[(0*8 + t)*68 + l] = ucf[t];
                ucW[(1*8 + t)*68 + l] = ucb[t];
            }
            WFENCE();

            // x_proj MFMA: A[row=(br,t)][k=d], K=64; F-set valid rows 0..7, B-set rows 8..15
            {
                const float* up = &ucW[(l&15)*68 + q*8];
                float av[8]; float4 a0, a1;
                a0 = *(const float4*)up; a1 = *(const float4*)(up+4);
                av[0]=a0.x;av[1]=a0.y;av[2]=a0.z;av[3]=a0.w;
                av[4]=a1.x;av[5]=a1.y;av[6]=a1.z;av[7]=a1.w;
                s16x8 A0h, A0l; pack_hilo8(av, A0h, A0l);
                a0 = *(const float4*)(up+32); a1 = *(const float4*)(up+36);
                av[0]=a0.x;av[1]=a0.y;av[2]=a0.z;av[3]=a0.w;
                av[4]=a1.x;av[5]=a1.y;av[6]=a1.z;av[7]=a1.w;
                s16x8 A1h, A1l; pack_hilo8(av, A1h, A1l);

                f32x4 accF[3], accB[3];
                #pragma unroll
                for (int nt=0; nt<3; nt++){
                    f32x4 a;
                    a = mfma16(A0l, BxF[nt][0], z4);
                    a = mfma16(A0h, BxF[nt][0], a);
                    a = mfma16(A1l, BxF[nt][1], a);
                    accF[nt] = mfma16(A1h, BxF[nt][1], a);
                    a = mfma16(A0l, BxB[nt][0], z4);
                    a = mfma16(A0h, BxB[nt][0], a);
                    a = mfma16(A1l, BxB[nt][1], a);
                    accB[nt] = mfma16(A1h, BxB[nt][1], a);
                }
                WFENCE();  // uc frag reads done before (next) rewrites; dbl writes next
                #pragma unroll
                for (int nt=0; nt<3; nt++){
                    int j = nt*16 + c16;
                    if (j < 34){
                        int jm = (j < 2) ? j : j + 2;
                        #pragma unroll
                        for (int r=0;r<4;r++){
                            int row = q*4 + r;
                            int t2 = row & 7, br = row >> 3;
                            float val = (q < 2) ? accF[nt][r] : accB[nt][r];
                            dblW[(t2*2 + br)*36 + jm] = val;
                        }
                    }
                }
            }
            WFENCE();

            // ---- selective scans (lane d keeps h[16]) ----
            float h[16], yf[8];
            #pragma unroll
            for (int si=0;si<16;si++) h[si]=0.0f;
            #pragma unroll
            for (int t=0;t<8;t++){
                const float* sl = &dblW[(t*2+0)*36];
                float delta = softplus_f(fmaf(sl[0], dtw0f, fmaf(sl[1], dtw1f, dtbf)));
                float du = delta * ucf[t];
                const float4* B4 = (const float4*)(sl+4);
                const float4* C4 = (const float4*)(sl+20);
                float y=0.0f;
                #pragma unroll
                for (int s4=0;s4<4;s4++){
                    float4 Bv=B4[s4], Cv=C4[s4];
                    float e0=__expf(delta*A_f[s4*4+0]);
                    h[s4*4+0]=fmaf(e0,h[s4*4+0],du*Bv.x); y=fmaf(h[s4*4+0],Cv.x,y);
                    float e1=__expf(delta*A_f[s4*4+1]);
                    h[s4*4+1]=fmaf(e1,h[s4*4+1],du*Bv.y); y=fmaf(h[s4*4+1],Cv.y,y);
                    float e2=__expf(delta*A_f[s4*4+2]);
                    h[s4*4+2]=fmaf(e2,h[s4*4+2],du*Bv.z); y=fmaf(h[s4*4+2],Cv.z,y);
                    float e3=__expf(delta*A_f[s4*4+3]);
                    h[s4*4+3]=fmaf(e3,h[s4*4+3],du*Bv.w); y=fmaf(h[s4*4+3],Cv.w,y);
                }
                yf[t] = fmaf(Dfv, ucf[t], y);
            }
            #pragma unroll
            for (int si=0;si<16;si++) h[si]=0.0f;
            #pragma unroll
            for (int tau=0;tau<8;tau++){
                const float* sl = &dblW[(tau*2+1)*36];
                float delta = softplus_f(fmaf(sl[0], dtw0b, fmaf(sl[1], dtw1b, dtbb)));
                float du = delta * ucb[tau];
                const float4* B4 = (const float4*)(sl+4);
                const float4* C4 = (const float4*)(sl+20);
                float y=0.0f;
                #pragma unroll
                for (int s4=0;s4<4;s4++){
                    float4 Bv=B4[s4], Cv=C4[s4];
                    float e0=__expf(delta*A_b[s4*4+0]);
                    h[s4*4+0]=fmaf(e0,h[s4*4+0],du*Bv.x); y=fmaf(h[s4*4+0],Cv.x,y);
                    float e1=__expf(delta*A_b[s4*4+1]);
                    h[s4*4+1]=fmaf(e1,h[s4*4+1],du*Bv.y); y=fmaf(h[s4*4+1],Cv.y,y);
                    float e2=__expf(delta*A_b[s4*4+2]);
                    h[s4*4+2]=fmaf(e2,h[s4*4+2],du*Bv.z); y=fmaf(h[s4*4+2],Cv.z,y);
                    float e3=__expf(delta*A_b[s4*4+3]);
                    h[s4*4+3]=fmaf(e3,h[s4*4+3],du*Bv.w); y=fmaf(h[s4*4+3],Cv.w,y);
                }
                float ytb = fmaf(Dbv, ucb[tau], y);
                int t = 7-tau;               // un-flip
                fyW[(s*8 + t)*68 + l] = (yf[t] + ytb) * siluz[t];   // y2 region
            }
            WFENCE();
        }

        // ---- out_proj MFMA: A[row=(s,t)][k=d], K=64; store + GN partials ----
        {
            const float* yp = &fyW[(l&15)*68 + q*8];
            float av[8]; float4 a0, a1;
            a0 = *(const float4*)yp; a1 = *(const float4*)(yp+4);
            av[0]=a0.x;av[1]=a0.y;av[2]=a0.z;av[3]=a0.w;
            av[4]=a1.x;av[5]=a1.y;av[6]=a1.z;av[7]=a1.w;
            s16x8 Y0h, Y0l; pack_hilo8(av, Y0h, Y0l);
            a0 = *(const float4*)(yp+32); a1 = *(const float4*)(yp+36);
            av[0]=a0.x;av[1]=a0.y;av[2]=a0.z;av[3]=a0.w;
            av[4]=a1.x;av[5]=a1.y;av[6]=a1.z;av[7]=a1.w;
            s16x8 Y1h, Y1l; pack_hilo8(av, Y1h, Y1l);

            #pragma unroll
            for (int nt=0; nt<2; nt++){
                f32x4 a;
                a = mfma16(Y0l, Bo[nt][0], z4);
                a = mfma16(Y0h, Bo[nt][0], a);
                a = mfma16(Y1l, Bo[nt][1], a);
                a = mfma16(Y1h, Bo[nt][1], a);
                #pragma unroll
                for (int r=0;r<4;r++){
                    int row = q*4 + r;
                    int s2 = row >> 3, t2 = row & 7;
                    int c = t2*32 + nt*16 + c16;
                    float val = a[r];
                    outb0[c*HWSZ + hw0 + s2] = val;
                    int gi = r >> 1;         // group = (q&1)*2 + gi
                    g_s[gi] += val;
                    g_q[gi] = fmaf(val, val, g_q[gi]);
                }
            }
        }
    }

    // ---- GN partial reduction: lanes sharing (q&1) hold same 2 groups ----
    #pragma unroll
    for (int gi=0; gi<2; gi++){
        float ss = g_s[gi], qq = g_q[gi];
        #pragma unroll
        for (int off=1; off<=8; off<<=1){
            ss += __shfl_xor(ss, off, 64);
            qq += __shfl_xor(qq, off, 64);
        }
        ss += __shfl_xor(ss, 32, 64);
        qq += __shfl_xor(qq, 32, 64);
        if ((l & 47) == 0){                 // lanes 0 and 16
            int g = ((l >> 4) & 1)*2 + gi;
            atomicAdd(&sums[b*8 + g*2],     ss);
            atomicAdd(&sums[b*8 + g*2 + 1], qq);
        }
    }
}

// Kernel 2: in-place GroupNorm apply + SiLU + residual. 4 floats/thread.
__global__ void spe_gn(float* __restrict__ out, const float* __restrict__ x,
                       const float* __restrict__ sums,
                       const float* __restrict__ gn_w, const float* __restrict__ gn_b)
{
    int i = (blockIdx.x*256 + threadIdx.x)*4;
    int c = (i >> 12) & 255;
    int b = i >> 20;
    int g = c >> 6;
    float s = sums[b*8 + g*2];
    float q = sums[b*8 + g*2 + 1];
    const float invN = 1.0f/262144.0f;   // 64 channels * 4096 hw
    float mean = s*invN;
    float var  = fmaf(-mean, mean, q*invN);
    float rstd = rsqrtf(var + 1e-5f);
    float wv = gn_w[c]*rstd;
    float bv = fmaf(-mean, wv, gn_b[c]);
    float4 o  = *(const float4*)(out + i);
    float4 xv = *(const float4*)(x + i);
    float v0 = fmaf(o.x, wv, bv);
    float v1 = fmaf(o.y, wv, bv);
    float v2 = fmaf(o.z, wv, bv);
    float v3 = fmaf(o.w, wv, bv);
    float4 res;
    res.x = xv.x + v0*sigmoid_f(v0);
    res.y = xv.y + v1*sigmoid_f(v1);
    res.z = xv.z + v2*sigmoid_f(v2);
    res.w = xv.w + v3*sigmoid_f(v3);
    *(float4*)(out + i) = res;
}

extern "C" void kernel_launch(void* const* d_in, const int* in_sizes, int n_in,
                              void* d_out, int out_size, void* d_ws, size_t ws_size,
                              hipStream_t stream) {
    (void)in_sizes; (void)n_in; (void)out_size; (void)ws_size;
    const float* x          = (const float*)d_in[0];
    const float* in_proj_w  = (const float*)d_in[1];
    const float* conv_w_f   = (const float*)d_in[2];
    const float* conv_b_f   = (const float*)d_in[3];
    const float* conv_w_b   = (const float*)d_in[4];
    const float* conv_b_b   = (const float*)d_in[5];
    const float* x_proj_w_f = (const float*)d_in[6];
    const float* x_proj_w_b = (const float*)d_in[7];
    const float* dt_proj_w_f= (const float*)d_in[8];
    const float* dt_proj_b_f= (const float*)d_in[9];
    const float* dt_proj_w_b= (const float*)d_in[10];
    const float* dt_proj_b_b= (const float*)d_in[11];
    const float* A_log_f    = (const float*)d_in[12];
    const float* A_log_b    = (const float*)d_in[13];
    const float* D_f        = (const float*)d_in[14];
    const float* D_b        = (const float*)d_in[15];
    const float* out_proj_w = (const float*)d_in[16];
    const float* gn_w       = (const float*)d_in[17];
    const float* gn_b       = (const float*)d_in[18];
    float* out  = (float*)d_out;
    float* sums = (float*)d_ws;

    hipMemsetAsync(d_ws, 0, 64*sizeof(float), stream);
    spe_main<<<2048, 256, 0, stream>>>(x, in_proj_w,
        conv_w_f, conv_b_f, conv_w_b, conv_b_b,
        x_proj_w_f, x_proj_w_b,
        dt_proj_w_f, dt_proj_b_f, dt_proj_w_b, dt_proj_b_b,
        A_log_f, A_log_b, D_f, D_b, out_proj_w, out, sums);
    spe_gn<<<8192, 256, 0, stream>>>(out, x, sums, gn_w, gn_b);
}